// Round 4
// baseline (2734.782 us; speedup 1.0000x reference)
//
#include <hip/hip_runtime.h>

// EventADModel: 2-frame 2-layer event GRU (H=256) + coord GRU (H=32, 1 step from 0)
// + fused linear fusion head, all via bf16 MFMA GEMMs with fused gate epilogues.
//
// R4: T3+T4 pipelined K-loop (double-buffered LDS, counted vmcnt(10), raw asm
//     barriers, ih/hh segments unified into one pipeline) + T5 setprio around
//     MFMA cluster. fusion_logits gets the same pipeline. xprep vectorized.
//
// Pipeline (all on `stream`):
//   prep: convert GRU weights to bf16; combine biases; fold fusion weights
//   xprep: batch_features -> A1 (x0 bf16 [N,64]), A3 cols 0..63 (x1)
//   K1: h0_t0 = gru(x0, 0)            A1 -> A3 cols 64..319
//   K2: h1_t0 = gru(h0_t0, 0)         A3 -> A4 cols 256..511
//   K3: h0_t1 = gru(x1, h0_t0)        A3 -> A4 cols 0..255
//   coord: coord GRU -> A5 cols 256..287 (+ zero pad 288..319)
//   K4: h1_t1 = gru(h0_t1, h1_t0)     A4 -> A5 cols 0..255
//   K5: logits = mask * (relu([h1_t1|coord]@WF^T + BF) @ W2^T + b2)

#define NROWS 245760   // B*T = 8192*30
#define TT 30
#define KC 64

typedef __attribute__((ext_vector_type(4))) float f32x4;
typedef __attribute__((ext_vector_type(8))) short bf16x8;
typedef __attribute__((ext_vector_type(4))) unsigned short u16x4;

__device__ __forceinline__ float bf2f(unsigned short u) {
    union { unsigned int u; float f; } v; v.u = ((unsigned int)u) << 16; return v.f;
}
__device__ __forceinline__ unsigned short f2bf(float f) {
    union { float f; unsigned int u; } v; v.f = f;
    unsigned int u = v.u;
    unsigned int r = u + 0x7fffu + ((u >> 16) & 1u);   // RNE
    return (unsigned short)(r >> 16);
}
__device__ __forceinline__ float fexp2c(float x) {
    return __builtin_amdgcn_exp2f(fminf(x, 80.f));
}
__device__ __forceinline__ float fsigmoid(float x) {
    return __builtin_amdgcn_rcpf(1.f + fexp2c(-1.44269504f * x));
}
__device__ __forceinline__ float ftanh(float x) {
    float t = fexp2c(-2.88539008f * x);
    return (1.f - t) * __builtin_amdgcn_rcpf(1.f + t);
}
__device__ __forceinline__ f32x4 mfma16(bf16x8 a, bf16x8 b, f32x4 c) {
    return __builtin_amdgcn_mfma_f32_16x16x32_bf16(a, b, c, 0, 0, 0);
}
// async global->LDS, 16B/lane. LDS dest is wave-uniform base + lane*16 (linear);
// source address is per-lane (pre-swizzled by caller).
__device__ __forceinline__ void gload16(const unsigned short* g, unsigned short* l) {
    __builtin_amdgcn_global_load_lds(
        (const __attribute__((address_space(1))) void*)g,
        (__attribute__((address_space(3))) void*)l, 16, 0, 0);
}

// ---------------- prep kernels ----------------

__global__ void cvt_bf16(const float* __restrict__ src, unsigned short* __restrict__ dst, int n) {
    int i = blockIdx.x * 256 + threadIdx.x;
    if (i < n) dst[i] = f2bf(src[i]);
}

// three same-size (768x256) weight conversions in one launch
__global__ void cvt3_bf16(const float* __restrict__ s0, const float* __restrict__ s1,
                          const float* __restrict__ s2, unsigned short* __restrict__ d0,
                          unsigned short* __restrict__ d1, unsigned short* __restrict__ d2) {
    int i = blockIdx.x * 256 + threadIdx.x;   // 768*256 elements each
    d0[i] = f2bf(s0[i]);
    d1[i] = f2bf(s1[i]);
    d2[i] = f2bf(s2[i]);
}

// combined bias arrays [4][256]: br=bih_r+bhh_r, bz=bih_z+bhh_z, bin=bih_n, bhn=bhh_n
__global__ void bias_prep(const float* __restrict__ bih0, const float* __restrict__ bhh0, float* __restrict__ BC0,
                          const float* __restrict__ bih1, const float* __restrict__ bhh1, float* __restrict__ BC1) {
    int j = threadIdx.x;  // 256
    BC0[j]       = bih0[j]       + bhh0[j];
    BC0[256 + j] = bih0[256 + j] + bhh0[256 + j];
    BC0[512 + j] = bih0[512 + j];
    BC0[768 + j] = bhh0[512 + j];
    BC1[j]       = bih1[j]       + bhh1[j];
    BC1[256 + j] = bih1[256 + j] + bhh1[256 + j];
    BC1[512 + j] = bih1[512 + j];
    BC1[768 + j] = bhh1[512 + j];
}

// WF[o][k] (o<128, k<320): k<256 -> (W1a@We)[o][k]; 256<=k<288 -> (W1b@Wc)[o][k-256]; else 0
// BF[o] = b1[o] + W1a[o]·be + W1b[o]·bc
__global__ void fuse_prep(const float* __restrict__ We, const float* __restrict__ be,
                          const float* __restrict__ Wc, const float* __restrict__ bc_,
                          const float* __restrict__ W1, const float* __restrict__ b1,
                          unsigned short* __restrict__ WF, float* __restrict__ BF) {
    int idx = blockIdx.x * 256 + threadIdx.x;
    if (idx >= 128 * 320) return;
    int o = idx / 320, k = idx - o * 320;
    float v = 0.f;
    if (k < 256) {
        for (int i = 0; i < 128; ++i) v += W1[o * 256 + i] * We[i * 256 + k];
    } else if (k < 288) {
        int kk = k - 256;
        for (int i = 0; i < 128; ++i) v += W1[o * 256 + 128 + i] * Wc[i * 32 + kk];
    }
    WF[o * 320 + k] = f2bf(v);
    if (k == 0) {
        float s = b1[o];
        for (int i = 0; i < 128; ++i) s += W1[o * 256 + i] * be[i];
        for (int i = 0; i < 128; ++i) s += W1[o * 256 + 128 + i] * bc_[i];
        BF[o] = s;
    }
}

// batch_features [B,2,T,64] -> A1 (x0, [N,64] bf16), A3 cols 0..63 (x1, stride 320)
__global__ void xprep(const float* __restrict__ bf, unsigned short* __restrict__ A1,
                      unsigned short* __restrict__ A3) {
    int i = blockIdx.x * 256 + threadIdx.x;  // exactly N*16 threads
    int n = i >> 4, q = i & 15;              // 4 cols per thread
    int b = n / TT, t = n - b * TT;
    const float* p = bf + ((size_t)(b * 2) * TT + t) * 64 + q * 4;
    float4 v0 = *(const float4*)(p);
    float4 v1 = *(const float4*)(p + TT * 64);
    u16x4 o0 = { f2bf(v0.x), f2bf(v0.y), f2bf(v0.z), f2bf(v0.w) };
    u16x4 o1 = { f2bf(v1.x), f2bf(v1.y), f2bf(v1.z), f2bf(v1.w) };
    *(u16x4*)(A1 + (size_t)n * 64 + q * 4)  = o0;
    *(u16x4*)(A3 + (size_t)n * 320 + q * 4) = o1;
}

// coord GRU single step from h=0; writes A5 cols 256..287, zeros 288..319
__global__ void coord_gru(const float* __restrict__ coords, const float* __restrict__ WihC,
                          const float* __restrict__ bihC, const float* __restrict__ bhhC,
                          unsigned short* __restrict__ A5) {
    int n = blockIdx.x * 256 + threadIdx.x;
    if (n >= NROWS) return;
    const float4 c = *(const float4*)(coords + (size_t)n * 4);
    unsigned short* o = A5 + (size_t)n * 320 + 256;
    for (int j = 0; j < 32; ++j) {
        float gr = WihC[j * 4 + 0] * c.x + WihC[j * 4 + 1] * c.y + WihC[j * 4 + 2] * c.z + WihC[j * 4 + 3] * c.w + bihC[j];
        int j2 = 32 + j;
        float gz = WihC[j2 * 4 + 0] * c.x + WihC[j2 * 4 + 1] * c.y + WihC[j2 * 4 + 2] * c.z + WihC[j2 * 4 + 3] * c.w + bihC[j2];
        int j3 = 64 + j;
        float gn = WihC[j3 * 4 + 0] * c.x + WihC[j3 * 4 + 1] * c.y + WihC[j3 * 4 + 2] * c.z + WihC[j3 * 4 + 3] * c.w + bihC[j3];
        float r = fsigmoid(gr + bhhC[j]);
        float z = fsigmoid(gz + bhhC[j2]);
        float nn = ftanh(gn + r * bhhC[j3]);
        o[j] = f2bf((1.f - z) * nn);
    }
    for (int j = 32; j < 64; ++j) o[j] = 0;
}

// ---------------- GRU GEMM ----------------
// LDS layout (both A and W): row-major [rows][64] bf16, granule g (16B) of row r
// stored at position g ^ (r&7). global_load_lds writes linearly; lane l's SOURCE
// granule is (l&7)^(l>>3)  [rule #21: linear dest + inverse-swizzled source].
__device__ __forceinline__ void gemm_compute(
    const unsigned short* sA, const unsigned short* sW,
    int lr, int lk, int wave, int xr,
    f32x4 (&aR)[2][4], f32x4 (&aZ)[2][4], f32x4 (&aG)[2][4]) {
    __builtin_amdgcn_s_setprio(1);
#pragma unroll
    for (int kk = 0; kk < 2; ++kk) {
        int kx = (kk * 32 + lk * 8) ^ xr;
        bf16x8 a0 = *(const bf16x8*)(sA + (wave * 32 + lr) * KC + kx);
        bf16x8 a1 = *(const bf16x8*)(sA + (wave * 32 + 16 + lr) * KC + kx);
#pragma unroll
        for (int t = 0; t < 12; ++t) {
            bf16x8 b = *(const bf16x8*)(sW + (t * 16 + lr) * KC + kx);
            int gi = t & 3;
            if (t < 4) {
                aR[0][gi] = mfma16(a0, b, aR[0][gi]);
                aR[1][gi] = mfma16(a1, b, aR[1][gi]);
            } else if (t < 8) {
                aZ[0][gi] = mfma16(a0, b, aZ[0][gi]);
                aZ[1][gi] = mfma16(a1, b, aZ[1][gi]);
            } else {
                aG[0][gi] = mfma16(a0, b, aG[0][gi]);
                aG[1][gi] = mfma16(a1, b, aG[1][gi]);
            }
        }
    }
    __builtin_amdgcn_s_setprio(0);
}

// block: 128 rows x 64 h-cols x 3 gates. 1D grid NROWS/128*4, XCD-swizzled.
// Pipelined: STAGE(s+1) -> vmcnt(10) -> barrier -> compute(s) -> barrier.
template <bool HAS_HH, bool HAS_HPREV>
__global__ __launch_bounds__(256, 2) void gru_gemm(
    const unsigned short* __restrict__ A, int lda,
    int Kih, const unsigned short* __restrict__ Wih,
    int Khh, const unsigned short* __restrict__ Whh,
    const float* __restrict__ bc,
    const unsigned short* __restrict__ hprev, int ldh,
    unsigned short* __restrict__ dst, int ldd) {
    __shared__ unsigned short sA[2][128 * KC];
    __shared__ unsigned short sW[2][192 * KC];
    const int tid = threadIdx.x;
    // XCD-bijective swizzle: nwg % 8 == 0, so chunked form is exact.
    const int nwg = gridDim.x;
    const int wgid = (blockIdx.x & 7) * (nwg >> 3) + (blockIdx.x >> 3);
    const int cb = wgid & 3;
    const int row0 = (wgid >> 2) * 128;
    const int lane = tid & 63, wave = tid >> 6;
    const int lr = lane & 15, lk = lane >> 4;
    const int xr = (lr & 7) * 8;
    const int gsrc = ((lane & 7) ^ (lane >> 3)) * 8;
    const int lrow = lane >> 3;

    const int nsteps0 = Kih >> 6;
    const int nsteps = nsteps0 + (HAS_HH ? (Khh >> 6) : 0);

    // per-lane global source base pointers (hoisted out of the K-loop)
    const unsigned short* pA[4];
#pragma unroll
    for (int it = 0; it < 4; ++it)
        pA[it] = A + (size_t)(row0 + (it * 4 + wave) * 8 + lrow) * lda + gsrc;
    const unsigned short* pWi[6];
    const unsigned short* pWh[6];
#pragma unroll
    for (int it = 0; it < 6; ++it) {
        int gw = it * 4 + wave;
        int t = gw >> 1, c = (gw & 1) * 8 + lrow;
        int grow = (t >> 2) * 256 + cb * 64 + (t & 3) * 16 + c;
        pWi[it] = Wih + (size_t)grow * Kih + gsrc;
        pWh[it] = HAS_HH ? (Whh + (size_t)grow * Khh + gsrc) : (Wih + gsrc);
    }

    f32x4 aR[2][4] = {}, aZ[2][4] = {}, aIN[2][4] = {}, aHN[2][4] = {};

    auto STAGE = [&](int s, int b) {
        const int acol = s * KC;                       // A col advances across segments
        const bool sg1 = HAS_HH && (s >= nsteps0);
        const int wcol = sg1 ? (s - nsteps0) * KC : acol;
#pragma unroll
        for (int it = 0; it < 4; ++it)
            gload16(pA[it] + acol, &sA[b][(it * 4 + wave) * 512]);
#pragma unroll
        for (int it = 0; it < 6; ++it)
            gload16((sg1 ? pWh[it] : pWi[it]) + wcol, &sW[b][(it * 4 + wave) * 512]);
    };

    STAGE(0, 0);
    for (int s = 0; s < nsteps; ++s) {
        const int b = s & 1;
        if (s + 1 < nsteps) {
            STAGE(s + 1, b ^ 1);
            asm volatile("s_waitcnt vmcnt(10)" ::: "memory");  // tile s landed; next 10 in flight
        } else {
            asm volatile("s_waitcnt vmcnt(0)" ::: "memory");
        }
        asm volatile("s_barrier" ::: "memory");
        if (!HAS_HH || s < nsteps0)
            gemm_compute(sA[b], sW[b], lr, lk, wave, xr, aR, aZ, aIN);
        else
            gemm_compute(sA[b], sW[b], lr, lk, wave, xr, aR, aZ, aHN);
        asm volatile("s_barrier" ::: "memory");  // reads done before next STAGE overwrites
    }

    // epilogue: gates
    const int jc = cb * 64;
    const int rb = row0 + wave * 32;
#pragma unroll
    for (int s = 0; s < 2; ++s) {
#pragma unroll
        for (int gi = 0; gi < 4; ++gi) {
            int j = jc + gi * 16 + lr;
            float br = bc[j], bz = bc[256 + j], bin = bc[512 + j], bhn = bc[768 + j];
#pragma unroll
            for (int q = 0; q < 4; ++q) {
                int row = rb + s * 16 + lk * 4 + q;
                float rg = fsigmoid(aR[s][gi][q] + br);
                float zg = fsigmoid(aZ[s][gi][q] + bz);
                float hn = HAS_HH ? aHN[s][gi][q] : 0.f;
                float ng = ftanh(aIN[s][gi][q] + bin + rg * (hn + bhn));
                float h = (1.f - zg) * ng;
                if (HAS_HPREV) h += zg * bf2f(hprev[(size_t)row * ldh + j]);
                dst[(size_t)row * ldd + j] = f2bf(h);
            }
        }
    }
}

// fusion + logits: hid = relu(A5 @ WF^T + BF); out = mask * (hid @ W2^T + b2)
// same pipelined staging (6 loads/wave/step, vmcnt(6))
__global__ __launch_bounds__(256, 3) void fusion_logits(
    const unsigned short* __restrict__ A,   // [N][320]
    const unsigned short* __restrict__ WF,  // [128][320]
    const float* __restrict__ BF, const float* __restrict__ W2, const float* __restrict__ b2,
    const int* __restrict__ mask, float* __restrict__ out) {
    __shared__ unsigned short sA[2][64 * KC];
    __shared__ unsigned short sW[2][128 * KC];
    const int tid = threadIdx.x, lane = tid & 63, wave = tid >> 6;
    const int lr = lane & 15, lk = lane >> 4;
    const int xr = (lr & 7) * 8;
    const int gsrc = ((lane & 7) ^ (lane >> 3)) * 8;
    const int lrow = lane >> 3;
    const int row0 = blockIdx.x * 64;
    f32x4 acc[8] = {};
    const unsigned short* pA[2];
#pragma unroll
    for (int it = 0; it < 2; ++it)
        pA[it] = A + (size_t)(row0 + (it * 4 + wave) * 8 + lrow) * 320 + gsrc;
    const unsigned short* pW[4];
#pragma unroll
    for (int it = 0; it < 4; ++it)
        pW[it] = WF + (size_t)((it * 4 + wave) * 8 + lrow) * 320 + gsrc;

    auto STAGE = [&](int s, int b) {
        const int col = s * KC;
#pragma unroll
        for (int it = 0; it < 2; ++it)
            gload16(pA[it] + col, &sA[b][(it * 4 + wave) * 512]);
#pragma unroll
        for (int it = 0; it < 4; ++it)
            gload16(pW[it] + col, &sW[b][(it * 4 + wave) * 512]);
    };

    STAGE(0, 0);
    for (int s = 0; s < 5; ++s) {
        const int b = s & 1;
        if (s + 1 < 5) {
            STAGE(s + 1, b ^ 1);
            asm volatile("s_waitcnt vmcnt(6)" ::: "memory");
        } else {
            asm volatile("s_waitcnt vmcnt(0)" ::: "memory");
        }
        asm volatile("s_barrier" ::: "memory");
        __builtin_amdgcn_s_setprio(1);
#pragma unroll
        for (int kk = 0; kk < 2; ++kk) {
            int kx = (kk * 32 + lk * 8) ^ xr;
            bf16x8 a = *(const bf16x8*)(&sA[b][0] + (wave * 16 + lr) * KC + kx);
#pragma unroll
            for (int t = 0; t < 8; ++t) {
                bf16x8 bb = *(const bf16x8*)(&sW[b][0] + (t * 16 + lr) * KC + kx);
                acc[t] = mfma16(a, bb, acc[t]);
            }
        }
        __builtin_amdgcn_s_setprio(0);
        asm volatile("s_barrier" ::: "memory");
    }
#pragma unroll
    for (int q = 0; q < 4; ++q) {
        float l0 = 0.f, l1 = 0.f;
#pragma unroll
        for (int t = 0; t < 8; ++t) {
            int j = t * 16 + lr;
            float h = acc[t][q] + BF[j];
            h = h > 0.f ? h : 0.f;
            l0 += h * W2[j];
            l1 += h * W2[128 + j];
        }
#pragma unroll
        for (int m = 1; m < 16; m <<= 1) {
            l0 += __shfl_xor(l0, m, 64);
            l1 += __shfl_xor(l1, m, 64);
        }
        if (lr == 0) {
            int row = row0 + wave * 16 + lk * 4 + q;
            float v0 = l0 + b2[0], v1 = l1 + b2[1];
            if (!mask[row]) { v0 = 0.f; v1 = 0.f; }  // valid_mask is int32 on device
            out[(size_t)row * 2]     = v0;
            out[(size_t)row * 2 + 1] = v1;
        }
    }
}

// ---------------- launch ----------------

extern "C" void kernel_launch(void* const* d_in, const int* in_sizes, int n_in,
                              void* d_out, int out_size, void* d_ws, size_t ws_size,
                              hipStream_t stream) {
    const float* bfeat  = (const float*)d_in[0];
    const float* coords = (const float*)d_in[1];
    const int* mask = (const int*)d_in[2];  // jnp bool -> int32 on device
    const float* Wih0 = (const float*)d_in[3];
    const float* Whh0 = (const float*)d_in[4];
    const float* bih0 = (const float*)d_in[5];
    const float* bhh0 = (const float*)d_in[6];
    const float* Wih1 = (const float*)d_in[7];
    const float* Whh1 = (const float*)d_in[8];
    const float* bih1 = (const float*)d_in[9];
    const float* bhh1 = (const float*)d_in[10];
    const float* WihC = (const float*)d_in[11];
    // d_in[12] = WhhC: unused (coord GRU starts from h=0)
    const float* bihC = (const float*)d_in[13];
    const float* bhhC = (const float*)d_in[14];
    const float* We = (const float*)d_in[15];
    const float* be = (const float*)d_in[16];
    const float* Wc = (const float*)d_in[17];
    const float* bc_ = (const float*)d_in[18];
    const float* W1 = (const float*)d_in[19];
    const float* b1 = (const float*)d_in[20];
    const float* W2 = (const float*)d_in[21];
    const float* b2 = (const float*)d_in[22];
    float* out = (float*)d_out;

    const size_t N = NROWS;
    char* ws = (char*)d_ws;
    unsigned short* A4 = (unsigned short*)ws;                       // [N,512]
    unsigned short* A1 = (unsigned short*)ws;                       // [N,64]  (aliases A4; dead before K2)
    unsigned short* A3 = (unsigned short*)(ws + N * 512 * 2);       // [N,320]
    unsigned short* A5 = A3;                                        // [N,320] (aliases A3; A3 dead after K3)
    char* wp = ws + N * 512 * 2 + N * 320 * 2;
    unsigned short* WB0  = (unsigned short*)wp; wp += 768 * 64 * 2;
    unsigned short* WBh0 = (unsigned short*)wp; wp += 768 * 256 * 2;
    unsigned short* WB1  = (unsigned short*)wp; wp += 768 * 256 * 2;
    unsigned short* WBh1 = (unsigned short*)wp; wp += 768 * 256 * 2;
    unsigned short* WF   = (unsigned short*)wp; wp += 128 * 320 * 2;
    float* BC0 = (float*)wp; wp += 1024 * 4;
    float* BC1 = (float*)wp; wp += 1024 * 4;
    float* BF  = (float*)wp; wp += 128 * 4;

    // prep
    cvt_bf16<<<192, 256, 0, stream>>>(Wih0, WB0, 768 * 64);
    cvt3_bf16<<<768, 256, 0, stream>>>(Whh0, Wih1, Whh1, WBh0, WB1, WBh1);
    bias_prep<<<1, 256, 0, stream>>>(bih0, bhh0, BC0, bih1, bhh1, BC1);
    fuse_prep<<<160, 256, 0, stream>>>(We, be, Wc, bc_, W1, b1, WF, BF);
    xprep<<<15360, 256, 0, stream>>>(bfeat, A1, A3);

    const int gg = (NROWS / 128) * 4;  // 7680, % 8 == 0
    // K1: h0_t0 (x0, no hh, no hprev)
    gru_gemm<false, false><<<gg, 256, 0, stream>>>(A1, 64, 64, WB0, 0, nullptr, BC0, nullptr, 0, A3 + 64, 320);
    // K2: h1_t0 (h0_t0, no hh, no hprev)
    gru_gemm<false, false><<<gg, 256, 0, stream>>>(A3 + 64, 320, 256, WB1, 0, nullptr, BC1, nullptr, 0, A4 + 256, 512);
    // K3: h0_t1 (x1 + h0_t0)
    gru_gemm<true, true><<<gg, 256, 0, stream>>>(A3, 320, 64, WB0, 256, WBh0, BC0, A3 + 64, 320, A4, 512);
    // coord GRU -> A5 cols 256..319 (must run after K3: A5 aliases A3)
    coord_gru<<<NROWS / 256, 256, 0, stream>>>(coords, WihC, bihC, bhhC, A5);
    // K4: h1_t1 (h0_t1 + h1_t0) -> A5 cols 0..255
    gru_gemm<true, true><<<gg, 256, 0, stream>>>(A4, 512, 256, WB1, 256, WBh1, BC1, A4 + 256, 512, A5, 320);
    // K5: fusion + logits
    fusion_logits<<<NROWS / 64, 256, 0, stream>>>(A5, WF, BF, W2, b2, mask, out);

    (void)in_sizes; (void)n_in; (void)out_size; (void)ws_size;
}

// Round 5
// 2036.676 us; speedup vs baseline: 1.3428x; 1.3428x over previous
//
#include <hip/hip_runtime.h>

// EventADModel: 2-frame 2-layer event GRU (H=256) + coord GRU (H=32, 1 step from 0)
// + fused linear fusion head, all via bf16 MFMA GEMMs with fused gate epilogues.
//
// R5: revert to R3's proven single-buffer/2-barrier gemm structure (R4's
//     dbuf+vmcnt pipeline spilled to scratch: WRITE_SIZE 184MB->3.28GB).
//     Keep cvt3 + vectorized xprep; bump launch_bounds to (256,4).
//
// Pipeline (all on `stream`):
//   prep: convert GRU weights to bf16; combine biases; fold fusion weights
//   xprep: batch_features -> A1 (x0 bf16 [N,64]), A3 cols 0..63 (x1)
//   K1: h0_t0 = gru(x0, 0)            A1 -> A3 cols 64..319
//   K2: h1_t0 = gru(h0_t0, 0)         A3 -> A4 cols 256..511
//   K3: h0_t1 = gru(x1, h0_t0)        A3 -> A4 cols 0..255
//   coord: coord GRU -> A5 cols 256..287 (+ zero pad 288..319)
//   K4: h1_t1 = gru(h0_t1, h1_t0)     A4 -> A5 cols 0..255
//   K5: logits = mask * (relu([h1_t1|coord]@WF^T + BF) @ W2^T + b2)

#define NROWS 245760   // B*T = 8192*30
#define TT 30
#define KC 64

typedef __attribute__((ext_vector_type(4))) float f32x4;
typedef __attribute__((ext_vector_type(8))) short bf16x8;
typedef __attribute__((ext_vector_type(4))) unsigned short u16x4;

__device__ __forceinline__ float bf2f(unsigned short u) {
    union { unsigned int u; float f; } v; v.u = ((unsigned int)u) << 16; return v.f;
}
__device__ __forceinline__ unsigned short f2bf(float f) {
    union { float f; unsigned int u; } v; v.f = f;
    unsigned int u = v.u;
    unsigned int r = u + 0x7fffu + ((u >> 16) & 1u);   // RNE
    return (unsigned short)(r >> 16);
}
__device__ __forceinline__ float fexp2c(float x) {
    return __builtin_amdgcn_exp2f(fminf(x, 80.f));
}
__device__ __forceinline__ float fsigmoid(float x) {
    return __builtin_amdgcn_rcpf(1.f + fexp2c(-1.44269504f * x));
}
__device__ __forceinline__ float ftanh(float x) {
    float t = fexp2c(-2.88539008f * x);
    return (1.f - t) * __builtin_amdgcn_rcpf(1.f + t);
}
__device__ __forceinline__ f32x4 mfma16(bf16x8 a, bf16x8 b, f32x4 c) {
    return __builtin_amdgcn_mfma_f32_16x16x32_bf16(a, b, c, 0, 0, 0);
}
// async global->LDS, 16B/lane. LDS dest is wave-uniform base + lane*16 (linear);
// source address is per-lane (pre-swizzled by caller).
__device__ __forceinline__ void gload16(const unsigned short* g, unsigned short* l) {
    __builtin_amdgcn_global_load_lds(
        (const __attribute__((address_space(1))) void*)g,
        (__attribute__((address_space(3))) void*)l, 16, 0, 0);
}

// ---------------- prep kernels ----------------

__global__ void cvt_bf16(const float* __restrict__ src, unsigned short* __restrict__ dst, int n) {
    int i = blockIdx.x * 256 + threadIdx.x;
    if (i < n) dst[i] = f2bf(src[i]);
}

// three same-size (768x256) weight conversions in one launch
__global__ void cvt3_bf16(const float* __restrict__ s0, const float* __restrict__ s1,
                          const float* __restrict__ s2, unsigned short* __restrict__ d0,
                          unsigned short* __restrict__ d1, unsigned short* __restrict__ d2) {
    int i = blockIdx.x * 256 + threadIdx.x;   // 768*256 elements each
    d0[i] = f2bf(s0[i]);
    d1[i] = f2bf(s1[i]);
    d2[i] = f2bf(s2[i]);
}

// combined bias arrays [4][256]: br=bih_r+bhh_r, bz=bih_z+bhh_z, bin=bih_n, bhn=bhh_n
__global__ void bias_prep(const float* __restrict__ bih0, const float* __restrict__ bhh0, float* __restrict__ BC0,
                          const float* __restrict__ bih1, const float* __restrict__ bhh1, float* __restrict__ BC1) {
    int j = threadIdx.x;  // 256
    BC0[j]       = bih0[j]       + bhh0[j];
    BC0[256 + j] = bih0[256 + j] + bhh0[256 + j];
    BC0[512 + j] = bih0[512 + j];
    BC0[768 + j] = bhh0[512 + j];
    BC1[j]       = bih1[j]       + bhh1[j];
    BC1[256 + j] = bih1[256 + j] + bhh1[256 + j];
    BC1[512 + j] = bih1[512 + j];
    BC1[768 + j] = bhh1[512 + j];
}

// WF[o][k] (o<128, k<320): k<256 -> (W1a@We)[o][k]; 256<=k<288 -> (W1b@Wc)[o][k-256]; else 0
// BF[o] = b1[o] + W1a[o]·be + W1b[o]·bc
__global__ void fuse_prep(const float* __restrict__ We, const float* __restrict__ be,
                          const float* __restrict__ Wc, const float* __restrict__ bc_,
                          const float* __restrict__ W1, const float* __restrict__ b1,
                          unsigned short* __restrict__ WF, float* __restrict__ BF) {
    int idx = blockIdx.x * 256 + threadIdx.x;
    if (idx >= 128 * 320) return;
    int o = idx / 320, k = idx - o * 320;
    float v = 0.f;
    if (k < 256) {
        for (int i = 0; i < 128; ++i) v += W1[o * 256 + i] * We[i * 256 + k];
    } else if (k < 288) {
        int kk = k - 256;
        for (int i = 0; i < 128; ++i) v += W1[o * 256 + 128 + i] * Wc[i * 32 + kk];
    }
    WF[o * 320 + k] = f2bf(v);
    if (k == 0) {
        float s = b1[o];
        for (int i = 0; i < 128; ++i) s += W1[o * 256 + i] * be[i];
        for (int i = 0; i < 128; ++i) s += W1[o * 256 + 128 + i] * bc_[i];
        BF[o] = s;
    }
}

// batch_features [B,2,T,64] -> A1 (x0, [N,64] bf16), A3 cols 0..63 (x1, stride 320)
__global__ void xprep(const float* __restrict__ bf, unsigned short* __restrict__ A1,
                      unsigned short* __restrict__ A3) {
    int i = blockIdx.x * 256 + threadIdx.x;  // exactly N*16 threads
    int n = i >> 4, q = i & 15;              // 4 cols per thread
    int b = n / TT, t = n - b * TT;
    const float* p = bf + ((size_t)(b * 2) * TT + t) * 64 + q * 4;
    float4 v0 = *(const float4*)(p);
    float4 v1 = *(const float4*)(p + TT * 64);
    u16x4 o0 = { f2bf(v0.x), f2bf(v0.y), f2bf(v0.z), f2bf(v0.w) };
    u16x4 o1 = { f2bf(v1.x), f2bf(v1.y), f2bf(v1.z), f2bf(v1.w) };
    *(u16x4*)(A1 + (size_t)n * 64 + q * 4)  = o0;
    *(u16x4*)(A3 + (size_t)n * 320 + q * 4) = o1;
}

// coord GRU single step from h=0; writes A5 cols 256..287, zeros 288..319
__global__ void coord_gru(const float* __restrict__ coords, const float* __restrict__ WihC,
                          const float* __restrict__ bihC, const float* __restrict__ bhhC,
                          unsigned short* __restrict__ A5) {
    int n = blockIdx.x * 256 + threadIdx.x;
    if (n >= NROWS) return;
    const float4 c = *(const float4*)(coords + (size_t)n * 4);
    unsigned short* o = A5 + (size_t)n * 320 + 256;
    for (int j = 0; j < 32; ++j) {
        float gr = WihC[j * 4 + 0] * c.x + WihC[j * 4 + 1] * c.y + WihC[j * 4 + 2] * c.z + WihC[j * 4 + 3] * c.w + bihC[j];
        int j2 = 32 + j;
        float gz = WihC[j2 * 4 + 0] * c.x + WihC[j2 * 4 + 1] * c.y + WihC[j2 * 4 + 2] * c.z + WihC[j2 * 4 + 3] * c.w + bihC[j2];
        int j3 = 64 + j;
        float gn = WihC[j3 * 4 + 0] * c.x + WihC[j3 * 4 + 1] * c.y + WihC[j3 * 4 + 2] * c.z + WihC[j3 * 4 + 3] * c.w + bihC[j3];
        float r = fsigmoid(gr + bhhC[j]);
        float z = fsigmoid(gz + bhhC[j2]);
        float nn = ftanh(gn + r * bhhC[j3]);
        o[j] = f2bf((1.f - z) * nn);
    }
    for (int j = 32; j < 64; ++j) o[j] = 0;
}

// ---------------- GRU GEMM ----------------
// LDS layout (both A and W): row-major [rows][64] bf16, granule g (16B) of row r
// stored at position g ^ (r&7). global_load_lds writes linearly (one wave insn =
// 8 LDS rows); lane l holds dest (row=base+(l>>3), pos=l&7) so its SOURCE granule
// is (l&7)^(l>>3)  [rule #21: linear dest + inverse-swizzled source + swizzled read].
__device__ __forceinline__ void gemm_phase(
    const unsigned short* __restrict__ Ag, int lda, int aoff, int Kp,
    const unsigned short* __restrict__ Wg,
    unsigned short* sA, unsigned short* sW,
    int row0, int cb, int tid,
    f32x4 (&aR)[2][4], f32x4 (&aZ)[2][4], f32x4 (&aG)[2][4]) {
    const int lane = tid & 63, wave = tid >> 6;
    const int lr = lane & 15, lk = lane >> 4;
    const int xr = (lr & 7) * 8;
    const int gsrc = ((lane & 7) ^ (lane >> 3)) * 8;  // source element offset within row
    const int lrow = lane >> 3;                        // row within 8-row group
    for (int kc = 0; kc < Kp; kc += KC) {
        __syncthreads();
        // stage A: 128 rows = 16 groups of 8 rows; 4 gloads/wave
#pragma unroll
        for (int it = 0; it < 4; ++it) {
            int grp = it * 4 + wave;
            const unsigned short* src = Ag + (size_t)(row0 + grp * 8 + lrow) * lda + aoff + kc + gsrc;
            gload16(src, sA + grp * 512);
        }
        // stage W: 192 rows (12 strips x 16) = 24 groups; 6 gloads/wave
#pragma unroll
        for (int it = 0; it < 6; ++it) {
            int gw = it * 4 + wave;
            int t = gw >> 1;                      // strip index 0..11
            int c = (gw & 1) * 8 + lrow;          // row within strip
            int grow = (t >> 2) * 256 + cb * 64 + (t & 3) * 16 + c;
            const unsigned short* src = Wg + (size_t)grow * Kp + kc + gsrc;
            gload16(src, sW + gw * 512);
        }
        __syncthreads();
#pragma unroll
        for (int kk = 0; kk < 2; ++kk) {
            int kx = (kk * 32 + lk * 8) ^ xr;
            bf16x8 a0 = *(const bf16x8*)(sA + (wave * 32 + lr) * KC + kx);
            bf16x8 a1 = *(const bf16x8*)(sA + (wave * 32 + 16 + lr) * KC + kx);
#pragma unroll
            for (int t = 0; t < 12; ++t) {
                bf16x8 b = *(const bf16x8*)(sW + (t * 16 + lr) * KC + kx);
                int gi = t & 3;
                if (t < 4) {
                    aR[0][gi] = mfma16(a0, b, aR[0][gi]);
                    aR[1][gi] = mfma16(a1, b, aR[1][gi]);
                } else if (t < 8) {
                    aZ[0][gi] = mfma16(a0, b, aZ[0][gi]);
                    aZ[1][gi] = mfma16(a1, b, aZ[1][gi]);
                } else {
                    aG[0][gi] = mfma16(a0, b, aG[0][gi]);
                    aG[1][gi] = mfma16(a1, b, aG[1][gi]);
                }
            }
        }
    }
}

// block: 128 rows x 64 h-cols. 1D grid NROWS/128*4, XCD-swizzled; cb = low 2 bits.
template <bool HAS_HH, bool HAS_HPREV>
__global__ __launch_bounds__(256, 4) void gru_gemm(
    const unsigned short* __restrict__ A, int lda,
    int Kih, const unsigned short* __restrict__ Wih,
    int Khh, const unsigned short* __restrict__ Whh,
    const float* __restrict__ bc,
    const unsigned short* __restrict__ hprev, int ldh,
    unsigned short* __restrict__ dst, int ldd) {
    __shared__ unsigned short sA[128 * KC];
    __shared__ unsigned short sW[192 * KC];
    const int tid = threadIdx.x;
    // XCD-bijective swizzle: nwg % 8 == 0, so chunked form is exact.
    const int nwg = gridDim.x;
    const int wgid = (blockIdx.x & 7) * (nwg >> 3) + (blockIdx.x >> 3);
    const int cb = wgid & 3;
    const int row0 = (wgid >> 2) * 128;
    f32x4 aR[2][4] = {}, aZ[2][4] = {}, aIN[2][4] = {}, aHN[2][4] = {};
    gemm_phase(A, lda, 0, Kih, Wih, sA, sW, row0, cb, tid, aR, aZ, aIN);
    if (HAS_HH)
        gemm_phase(A, lda, Kih, Khh, Whh, sA, sW, row0, cb, tid, aR, aZ, aHN);
    // epilogue: gates
    const int lane = tid & 63, wave = tid >> 6;
    const int lr = lane & 15, lk = lane >> 4;
    const int jc = cb * 64;
    const int rb = row0 + wave * 32;
#pragma unroll
    for (int s = 0; s < 2; ++s) {
#pragma unroll
        for (int gi = 0; gi < 4; ++gi) {
            int j = jc + gi * 16 + lr;
            float br = bc[j], bz = bc[256 + j], bin = bc[512 + j], bhn = bc[768 + j];
#pragma unroll
            for (int q = 0; q < 4; ++q) {
                int row = rb + s * 16 + lk * 4 + q;
                float rg = fsigmoid(aR[s][gi][q] + br);
                float zg = fsigmoid(aZ[s][gi][q] + bz);
                float hn = HAS_HH ? aHN[s][gi][q] : 0.f;
                float ng = ftanh(aIN[s][gi][q] + bin + rg * (hn + bhn));
                float h = (1.f - zg) * ng;
                if (HAS_HPREV) h += zg * bf2f(hprev[(size_t)row * ldh + j]);
                dst[(size_t)row * ldd + j] = f2bf(h);
            }
        }
    }
}

// fusion + logits: hid = relu(A5 @ WF^T + BF); out = mask * (hid @ W2^T + b2)
__global__ __launch_bounds__(256, 4) void fusion_logits(
    const unsigned short* __restrict__ A,   // [N][320]
    const unsigned short* __restrict__ WF,  // [128][320]
    const float* __restrict__ BF, const float* __restrict__ W2, const float* __restrict__ b2,
    const int* __restrict__ mask, float* __restrict__ out) {
    __shared__ unsigned short sA[64 * KC];
    __shared__ unsigned short sW[128 * KC];
    const int tid = threadIdx.x, lane = tid & 63, wave = tid >> 6;
    const int lr = lane & 15, lk = lane >> 4;
    const int xr = (lr & 7) * 8;
    const int gsrc = ((lane & 7) ^ (lane >> 3)) * 8;
    const int lrow = lane >> 3;
    const int row0 = blockIdx.x * 64;
    f32x4 acc[8] = {};
    for (int kc = 0; kc < 320; kc += KC) {
        __syncthreads();
#pragma unroll
        for (int it = 0; it < 2; ++it) {
            int grp = it * 4 + wave;   // 8 groups = 64 rows
            const unsigned short* src = A + (size_t)(row0 + grp * 8 + lrow) * 320 + kc + gsrc;
            gload16(src, sA + grp * 512);
        }
#pragma unroll
        for (int it = 0; it < 4; ++it) {
            int gw = it * 4 + wave;    // 16 groups = 128 rows
            const unsigned short* src = WF + (size_t)(gw * 8 + lrow) * 320 + kc + gsrc;
            gload16(src, sW + gw * 512);
        }
        __syncthreads();
#pragma unroll
        for (int kk = 0; kk < 2; ++kk) {
            int kx = (kk * 32 + lk * 8) ^ xr;
            bf16x8 a = *(const bf16x8*)(sA + (wave * 16 + lr) * KC + kx);
#pragma unroll
            for (int t = 0; t < 8; ++t) {
                bf16x8 b = *(const bf16x8*)(sW + (t * 16 + lr) * KC + kx);
                acc[t] = mfma16(a, b, acc[t]);
            }
        }
    }
#pragma unroll
    for (int q = 0; q < 4; ++q) {
        float l0 = 0.f, l1 = 0.f;
#pragma unroll
        for (int t = 0; t < 8; ++t) {
            int j = t * 16 + lr;
            float h = acc[t][q] + BF[j];
            h = h > 0.f ? h : 0.f;
            l0 += h * W2[j];
            l1 += h * W2[128 + j];
        }
#pragma unroll
        for (int m = 1; m < 16; m <<= 1) {
            l0 += __shfl_xor(l0, m, 64);
            l1 += __shfl_xor(l1, m, 64);
        }
        if (lr == 0) {
            int row = row0 + wave * 16 + lk * 4 + q;
            float v0 = l0 + b2[0], v1 = l1 + b2[1];
            if (!mask[row]) { v0 = 0.f; v1 = 0.f; }  // valid_mask is int32 on device
            out[(size_t)row * 2]     = v0;
            out[(size_t)row * 2 + 1] = v1;
        }
    }
}

// ---------------- launch ----------------

extern "C" void kernel_launch(void* const* d_in, const int* in_sizes, int n_in,
                              void* d_out, int out_size, void* d_ws, size_t ws_size,
                              hipStream_t stream) {
    const float* bfeat  = (const float*)d_in[0];
    const float* coords = (const float*)d_in[1];
    const int* mask = (const int*)d_in[2];  // jnp bool -> int32 on device
    const float* Wih0 = (const float*)d_in[3];
    const float* Whh0 = (const float*)d_in[4];
    const float* bih0 = (const float*)d_in[5];
    const float* bhh0 = (const float*)d_in[6];
    const float* Wih1 = (const float*)d_in[7];
    const float* Whh1 = (const float*)d_in[8];
    const float* bih1 = (const float*)d_in[9];
    const float* bhh1 = (const float*)d_in[10];
    const float* WihC = (const float*)d_in[11];
    // d_in[12] = WhhC: unused (coord GRU starts from h=0)
    const float* bihC = (const float*)d_in[13];
    const float* bhhC = (const float*)d_in[14];
    const float* We = (const float*)d_in[15];
    const float* be = (const float*)d_in[16];
    const float* Wc = (const float*)d_in[17];
    const float* bc_ = (const float*)d_in[18];
    const float* W1 = (const float*)d_in[19];
    const float* b1 = (const float*)d_in[20];
    const float* W2 = (const float*)d_in[21];
    const float* b2 = (const float*)d_in[22];
    float* out = (float*)d_out;

    const size_t N = NROWS;
    char* ws = (char*)d_ws;
    unsigned short* A4 = (unsigned short*)ws;                       // [N,512]
    unsigned short* A1 = (unsigned short*)ws;                       // [N,64]  (aliases A4; dead before K2)
    unsigned short* A3 = (unsigned short*)(ws + N * 512 * 2);       // [N,320]
    unsigned short* A5 = A3;                                        // [N,320] (aliases A3; A3 dead after K3)
    char* wp = ws + N * 512 * 2 + N * 320 * 2;
    unsigned short* WB0  = (unsigned short*)wp; wp += 768 * 64 * 2;
    unsigned short* WBh0 = (unsigned short*)wp; wp += 768 * 256 * 2;
    unsigned short* WB1  = (unsigned short*)wp; wp += 768 * 256 * 2;
    unsigned short* WBh1 = (unsigned short*)wp; wp += 768 * 256 * 2;
    unsigned short* WF   = (unsigned short*)wp; wp += 128 * 320 * 2;
    float* BC0 = (float*)wp; wp += 1024 * 4;
    float* BC1 = (float*)wp; wp += 1024 * 4;
    float* BF  = (float*)wp; wp += 128 * 4;

    // prep
    cvt_bf16<<<192, 256, 0, stream>>>(Wih0, WB0, 768 * 64);
    cvt3_bf16<<<768, 256, 0, stream>>>(Whh0, Wih1, Whh1, WBh0, WB1, WBh1);
    bias_prep<<<1, 256, 0, stream>>>(bih0, bhh0, BC0, bih1, bhh1, BC1);
    fuse_prep<<<160, 256, 0, stream>>>(We, be, Wc, bc_, W1, b1, WF, BF);
    xprep<<<15360, 256, 0, stream>>>(bfeat, A1, A3);

    const int gg = (NROWS / 128) * 4;  // 7680, % 8 == 0
    // K1: h0_t0 (x0, no hh, no hprev)
    gru_gemm<false, false><<<gg, 256, 0, stream>>>(A1, 64, 64, WB0, 0, nullptr, BC0, nullptr, 0, A3 + 64, 320);
    // K2: h1_t0 (h0_t0, no hh, no hprev)
    gru_gemm<false, false><<<gg, 256, 0, stream>>>(A3 + 64, 320, 256, WB1, 0, nullptr, BC1, nullptr, 0, A4 + 256, 512);
    // K3: h0_t1 (x1 + h0_t0)
    gru_gemm<true, true><<<gg, 256, 0, stream>>>(A3, 320, 64, WB0, 256, WBh0, BC0, A3 + 64, 320, A4, 512);
    // coord GRU -> A5 cols 256..319 (must run after K3: A5 aliases A3)
    coord_gru<<<NROWS / 256, 256, 0, stream>>>(coords, WihC, bihC, bhhC, A5);
    // K4: h1_t1 (h0_t1 + h1_t0) -> A5 cols 0..255
    gru_gemm<true, true><<<gg, 256, 0, stream>>>(A4, 512, 256, WB1, 256, WBh1, BC1, A4 + 256, 512, A5, 320);
    // K5: fusion + logits
    fusion_logits<<<NROWS / 64, 256, 0, stream>>>(A5, WF, BF, W2, b2, mask, out);

    (void)in_sizes; (void)n_in; (void)out_size; (void)ws_size;
}

// Round 6
// 791.012 us; speedup vs baseline: 3.4573x; 2.5748x over previous
//
#include <hip/hip_runtime.h>

// EventADModel: 2-frame 2-layer event GRU (H=256) + coord GRU (H=32, 1 step from 0)
// + fused linear fusion head, all via bf16 MFMA GEMMs with fused gate epilogues.
//
// R6: R3 structure (single-buffer, 2-barrier K-loop, launch_bounds(256,3) —
//     the ONLY occupancy that fits 128 AGPR acc + ~84 arch VGPR without
//     spilling; R4/R5 both proved deviations spill to scratch) with the MFMA
//     shape switched 16x16x32 -> 32x32x16: same acc reg count, same LDS bytes,
//     -17% MFMA cycles, half the MFMA instruction count, wider C-store.
//
// Pipeline (all on `stream`):
//   prep: convert GRU weights to bf16; combine biases; fold fusion weights
//   xprep: batch_features -> A1 (x0 bf16 [N,64]), A3 cols 0..63 (x1)
//   K1: h0_t0 = gru(x0, 0)            A1 -> A3 cols 64..319
//   K2: h1_t0 = gru(h0_t0, 0)         A3 -> A4 cols 256..511
//   K3: h0_t1 = gru(x1, h0_t0)        A3 -> A4 cols 0..255
//   coord: coord GRU -> A5 cols 256..287 (+ zero pad 288..319)
//   K4: h1_t1 = gru(h0_t1, h1_t0)     A4 -> A5 cols 0..255
//   K5: logits = mask * (relu([h1_t1|coord]@WF^T + BF) @ W2^T + b2)

#define NROWS 245760   // B*T = 8192*30
#define TT 30
#define KC 64

typedef __attribute__((ext_vector_type(4))) float f32x4;
typedef __attribute__((ext_vector_type(16))) float f32x16;
typedef __attribute__((ext_vector_type(8))) short bf16x8;
typedef __attribute__((ext_vector_type(4))) unsigned short u16x4;

__device__ __forceinline__ float bf2f(unsigned short u) {
    union { unsigned int u; float f; } v; v.u = ((unsigned int)u) << 16; return v.f;
}
__device__ __forceinline__ unsigned short f2bf(float f) {
    union { float f; unsigned int u; } v; v.f = f;
    unsigned int u = v.u;
    unsigned int r = u + 0x7fffu + ((u >> 16) & 1u);   // RNE
    return (unsigned short)(r >> 16);
}
__device__ __forceinline__ float fexp2c(float x) {
    return __builtin_amdgcn_exp2f(fminf(x, 80.f));
}
__device__ __forceinline__ float fsigmoid(float x) {
    return __builtin_amdgcn_rcpf(1.f + fexp2c(-1.44269504f * x));
}
__device__ __forceinline__ float ftanh(float x) {
    float t = fexp2c(-2.88539008f * x);
    return (1.f - t) * __builtin_amdgcn_rcpf(1.f + t);
}
__device__ __forceinline__ f32x16 mfma32(bf16x8 a, bf16x8 b, f32x16 c) {
    return __builtin_amdgcn_mfma_f32_32x32x16_bf16(a, b, c, 0, 0, 0);
}
__device__ __forceinline__ f32x4 mfma16(bf16x8 a, bf16x8 b, f32x4 c) {
    return __builtin_amdgcn_mfma_f32_16x16x32_bf16(a, b, c, 0, 0, 0);
}
// async global->LDS, 16B/lane. LDS dest is wave-uniform base + lane*16 (linear);
// source address is per-lane (pre-swizzled by caller).
__device__ __forceinline__ void gload16(const unsigned short* g, unsigned short* l) {
    __builtin_amdgcn_global_load_lds(
        (const __attribute__((address_space(1))) void*)g,
        (__attribute__((address_space(3))) void*)l, 16, 0, 0);
}

// ---------------- prep kernels ----------------

__global__ void cvt_bf16(const float* __restrict__ src, unsigned short* __restrict__ dst, int n) {
    int i = blockIdx.x * 256 + threadIdx.x;
    if (i < n) dst[i] = f2bf(src[i]);
}

// three same-size (768x256) weight conversions in one launch
__global__ void cvt3_bf16(const float* __restrict__ s0, const float* __restrict__ s1,
                          const float* __restrict__ s2, unsigned short* __restrict__ d0,
                          unsigned short* __restrict__ d1, unsigned short* __restrict__ d2) {
    int i = blockIdx.x * 256 + threadIdx.x;   // 768*256 elements each
    d0[i] = f2bf(s0[i]);
    d1[i] = f2bf(s1[i]);
    d2[i] = f2bf(s2[i]);
}

// combined bias arrays [4][256]: br=bih_r+bhh_r, bz=bih_z+bhh_z, bin=bih_n, bhn=bhh_n
__global__ void bias_prep(const float* __restrict__ bih0, const float* __restrict__ bhh0, float* __restrict__ BC0,
                          const float* __restrict__ bih1, const float* __restrict__ bhh1, float* __restrict__ BC1) {
    int j = threadIdx.x;  // 256
    BC0[j]       = bih0[j]       + bhh0[j];
    BC0[256 + j] = bih0[256 + j] + bhh0[256 + j];
    BC0[512 + j] = bih0[512 + j];
    BC0[768 + j] = bhh0[512 + j];
    BC1[j]       = bih1[j]       + bhh1[j];
    BC1[256 + j] = bih1[256 + j] + bhh1[256 + j];
    BC1[512 + j] = bih1[512 + j];
    BC1[768 + j] = bhh1[512 + j];
}

// WF[o][k] (o<128, k<320): k<256 -> (W1a@We)[o][k]; 256<=k<288 -> (W1b@Wc)[o][k-256]; else 0
// BF[o] = b1[o] + W1a[o]·be + W1b[o]·bc
__global__ void fuse_prep(const float* __restrict__ We, const float* __restrict__ be,
                          const float* __restrict__ Wc, const float* __restrict__ bc_,
                          const float* __restrict__ W1, const float* __restrict__ b1,
                          unsigned short* __restrict__ WF, float* __restrict__ BF) {
    int idx = blockIdx.x * 256 + threadIdx.x;
    if (idx >= 128 * 320) return;
    int o = idx / 320, k = idx - o * 320;
    float v = 0.f;
    if (k < 256) {
        for (int i = 0; i < 128; ++i) v += W1[o * 256 + i] * We[i * 256 + k];
    } else if (k < 288) {
        int kk = k - 256;
        for (int i = 0; i < 128; ++i) v += W1[o * 256 + 128 + i] * Wc[i * 32 + kk];
    }
    WF[o * 320 + k] = f2bf(v);
    if (k == 0) {
        float s = b1[o];
        for (int i = 0; i < 128; ++i) s += W1[o * 256 + i] * be[i];
        for (int i = 0; i < 128; ++i) s += W1[o * 256 + 128 + i] * bc_[i];
        BF[o] = s;
    }
}

// batch_features [B,2,T,64] -> A1 (x0, [N,64] bf16), A3 cols 0..63 (x1, stride 320)
__global__ void xprep(const float* __restrict__ bf, unsigned short* __restrict__ A1,
                      unsigned short* __restrict__ A3) {
    int i = blockIdx.x * 256 + threadIdx.x;  // exactly N*16 threads
    int n = i >> 4, q = i & 15;              // 4 cols per thread
    int b = n / TT, t = n - b * TT;
    const float* p = bf + ((size_t)(b * 2) * TT + t) * 64 + q * 4;
    float4 v0 = *(const float4*)(p);
    float4 v1 = *(const float4*)(p + TT * 64);
    u16x4 o0 = { f2bf(v0.x), f2bf(v0.y), f2bf(v0.z), f2bf(v0.w) };
    u16x4 o1 = { f2bf(v1.x), f2bf(v1.y), f2bf(v1.z), f2bf(v1.w) };
    *(u16x4*)(A1 + (size_t)n * 64 + q * 4)  = o0;
    *(u16x4*)(A3 + (size_t)n * 320 + q * 4) = o1;
}

// coord GRU single step from h=0; writes A5 cols 256..287, zeros 288..319
__global__ void coord_gru(const float* __restrict__ coords, const float* __restrict__ WihC,
                          const float* __restrict__ bihC, const float* __restrict__ bhhC,
                          unsigned short* __restrict__ A5) {
    int n = blockIdx.x * 256 + threadIdx.x;
    if (n >= NROWS) return;
    const float4 c = *(const float4*)(coords + (size_t)n * 4);
    unsigned short* o = A5 + (size_t)n * 320 + 256;
    for (int j = 0; j < 32; ++j) {
        float gr = WihC[j * 4 + 0] * c.x + WihC[j * 4 + 1] * c.y + WihC[j * 4 + 2] * c.z + WihC[j * 4 + 3] * c.w + bihC[j];
        int j2 = 32 + j;
        float gz = WihC[j2 * 4 + 0] * c.x + WihC[j2 * 4 + 1] * c.y + WihC[j2 * 4 + 2] * c.z + WihC[j2 * 4 + 3] * c.w + bihC[j2];
        int j3 = 64 + j;
        float gn = WihC[j3 * 4 + 0] * c.x + WihC[j3 * 4 + 1] * c.y + WihC[j3 * 4 + 2] * c.z + WihC[j3 * 4 + 3] * c.w + bihC[j3];
        float r = fsigmoid(gr + bhhC[j]);
        float z = fsigmoid(gz + bhhC[j2]);
        float nn = ftanh(gn + r * bhhC[j3]);
        o[j] = f2bf((1.f - z) * nn);
    }
    for (int j = 32; j < 64; ++j) o[j] = 0;
}

// ---------------- GRU GEMM (32x32x16 MFMA) ----------------
// LDS layout (both A and W): row-major [rows][64] bf16, granule g (16B) of row r
// stored at position g ^ (r&7). global_load_lds writes linearly; lane l's SOURCE
// granule is (l&7)^(l>>3)  [rule #21: linear dest + inverse-swizzled source].
// sW holds 6 strips x 32 rows: strip u = gate(u>>1)*256 + cb*64 + (u&1)*32.
// Fragment mapping (32x32x16): A row=l&31 k=(l>>5)*8+j; B col=l&31 k same;
// C/D col=l&31, row=(reg&3)+8*(reg>>2)+4*(l>>5)  [C/D verified m74/m101].
__device__ __forceinline__ void gemm_phase(
    const unsigned short* __restrict__ Ag, int lda, int aoff, int Kp,
    const unsigned short* __restrict__ Wg,
    unsigned short* sA, unsigned short* sW,
    int row0, int cb, int tid,
    f32x16 (&aR)[2], f32x16 (&aZ)[2], f32x16 (&aG)[2]) {
    const int lane = tid & 63, wave = tid >> 6;
    const int l31 = lane & 31;
    const int kg = lane >> 5;
    const int xr = (lane & 7) * 8;                    // read swizzle (row&7 == lane&7)
    const int gsrc = ((lane & 7) ^ (lane >> 3)) * 8;  // store-side inverse swizzle
    const int lrow = lane >> 3;                        // row within 8-row store group
    for (int kc = 0; kc < Kp; kc += KC) {
        __syncthreads();
        // stage A: 128 rows = 16 groups of 8 rows; 4 gloads/wave
#pragma unroll
        for (int it = 0; it < 4; ++it) {
            int grp = it * 4 + wave;
            const unsigned short* src = Ag + (size_t)(row0 + grp * 8 + lrow) * lda + aoff + kc + gsrc;
            gload16(src, sA + grp * 512);
        }
        // stage W: 6 strips x 32 rows = 24 groups of 8 rows; 6 gloads/wave
#pragma unroll
        for (int it = 0; it < 6; ++it) {
            int gw = it * 4 + wave;
            int u = gw >> 2;                       // strip index 0..5
            int cr = (gw & 3) * 8 + lrow;          // row within strip
            int grow = (u >> 1) * 256 + cb * 64 + (u & 1) * 32 + cr;
            const unsigned short* src = Wg + (size_t)grow * Kp + kc + gsrc;
            gload16(src, sW + gw * 512);
        }
        __syncthreads();
        const unsigned short* pa = sA + (wave * 32 + l31) * KC;
#pragma unroll
        for (int s = 0; s < 4; ++s) {
            int kx = (s * 16 + kg * 8) ^ xr;
            bf16x8 a = *(const bf16x8*)(pa + kx);
#pragma unroll
            for (int u = 0; u < 6; ++u) {
                bf16x8 b = *(const bf16x8*)(sW + (u * 32 + l31) * KC + kx);
                int ct = u & 1;
                if (u < 2)      aR[ct] = mfma32(a, b, aR[ct]);
                else if (u < 4) aZ[ct] = mfma32(a, b, aZ[ct]);
                else            aG[ct] = mfma32(a, b, aG[ct]);
            }
        }
    }
}

// block: 128 rows x 64 h-cols. 1D grid NROWS/128*4, XCD-swizzled; cb = low 2 bits.
template <bool HAS_HH, bool HAS_HPREV>
__global__ __launch_bounds__(256, 3) void gru_gemm(
    const unsigned short* __restrict__ A, int lda,
    int Kih, const unsigned short* __restrict__ Wih,
    int Khh, const unsigned short* __restrict__ Whh,
    const float* __restrict__ bc,
    const unsigned short* __restrict__ hprev, int ldh,
    unsigned short* __restrict__ dst, int ldd) {
    __shared__ unsigned short sA[128 * KC];
    __shared__ unsigned short sW[192 * KC];
    const int tid = threadIdx.x;
    // XCD-bijective swizzle: nwg % 8 == 0, so chunked form is exact.
    const int nwg = gridDim.x;
    const int wgid = (blockIdx.x & 7) * (nwg >> 3) + (blockIdx.x >> 3);
    const int cb = wgid & 3;
    const int row0 = (wgid >> 2) * 128;
    f32x16 aR[2] = {}, aZ[2] = {}, aIN[2] = {}, aHN[2] = {};
    gemm_phase(A, lda, 0, Kih, Wih, sA, sW, row0, cb, tid, aR, aZ, aIN);
    if (HAS_HH)
        gemm_phase(A, lda, Kih, Khh, Whh, sA, sW, row0, cb, tid, aR, aZ, aHN);
    // epilogue: gates. C/D: col = jc + ct*32 + (l&31), row = rb + (i&3) + 8*(i>>2)
    const int lane = tid & 63, wave = tid >> 6;
    const int l31 = lane & 31, kg = lane >> 5;
    const int jc = cb * 64;
    const int rb = row0 + wave * 32 + kg * 4;
#pragma unroll
    for (int ct = 0; ct < 2; ++ct) {
        int j = jc + ct * 32 + l31;
        float br = bc[j], bz = bc[256 + j], bin = bc[512 + j], bhn = bc[768 + j];
#pragma unroll
        for (int i = 0; i < 16; ++i) {
            int row = rb + (i & 3) + 8 * (i >> 2);
            float rg = fsigmoid(aR[ct][i] + br);
            float zg = fsigmoid(aZ[ct][i] + bz);
            float hn = HAS_HH ? aHN[ct][i] : 0.f;
            float ng = ftanh(aIN[ct][i] + bin + rg * (hn + bhn));
            float h = (1.f - zg) * ng;
            if (HAS_HPREV) h += zg * bf2f(hprev[(size_t)row * ldh + j]);
            dst[(size_t)row * ldd + j] = f2bf(h);
        }
    }
}

// fusion + logits: hid = relu(A5 @ WF^T + BF); out = mask * (hid @ W2^T + b2)
__global__ __launch_bounds__(256, 3) void fusion_logits(
    const unsigned short* __restrict__ A,   // [N][320]
    const unsigned short* __restrict__ WF,  // [128][320]
    const float* __restrict__ BF, const float* __restrict__ W2, const float* __restrict__ b2,
    const int* __restrict__ mask, float* __restrict__ out) {
    __shared__ unsigned short sA[64 * KC];
    __shared__ unsigned short sW[128 * KC];
    const int tid = threadIdx.x, lane = tid & 63, wave = tid >> 6;
    const int lr = lane & 15, lk = lane >> 4;
    const int xr = (lr & 7) * 8;
    const int gsrc = ((lane & 7) ^ (lane >> 3)) * 8;
    const int lrow = lane >> 3;
    const int row0 = blockIdx.x * 64;
    f32x4 acc[8] = {};
    for (int kc = 0; kc < 320; kc += KC) {
        __syncthreads();
#pragma unroll
        for (int it = 0; it < 2; ++it) {
            int grp = it * 4 + wave;   // 8 groups = 64 rows
            const unsigned short* src = A + (size_t)(row0 + grp * 8 + lrow) * 320 + kc + gsrc;
            gload16(src, sA + grp * 512);
        }
#pragma unroll
        for (int it = 0; it < 4; ++it) {
            int gw = it * 4 + wave;    // 16 groups = 128 rows
            const unsigned short* src = WF + (size_t)(gw * 8 + lrow) * 320 + kc + gsrc;
            gload16(src, sW + gw * 512);
        }
        __syncthreads();
#pragma unroll
        for (int kk = 0; kk < 2; ++kk) {
            int kx = (kk * 32 + lk * 8) ^ xr;
            bf16x8 a = *(const bf16x8*)(sA + (wave * 16 + lr) * KC + kx);
#pragma unroll
            for (int t = 0; t < 8; ++t) {
                bf16x8 b = *(const bf16x8*)(sW + (t * 16 + lr) * KC + kx);
                acc[t] = mfma16(a, b, acc[t]);
            }
        }
    }
#pragma unroll
    for (int q = 0; q < 4; ++q) {
        float l0 = 0.f, l1 = 0.f;
#pragma unroll
        for (int t = 0; t < 8; ++t) {
            int j = t * 16 + lr;
            float h = acc[t][q] + BF[j];
            h = h > 0.f ? h : 0.f;
            l0 += h * W2[j];
            l1 += h * W2[128 + j];
        }
#pragma unroll
        for (int m = 1; m < 16; m <<= 1) {
            l0 += __shfl_xor(l0, m, 64);
            l1 += __shfl_xor(l1, m, 64);
        }
        if (lr == 0) {
            int row = row0 + wave * 16 + lk * 4 + q;
            float v0 = l0 + b2[0], v1 = l1 + b2[1];
            if (!mask[row]) { v0 = 0.f; v1 = 0.f; }  // valid_mask is int32 on device
            out[(size_t)row * 2]     = v0;
            out[(size_t)row * 2 + 1] = v1;
        }
    }
}

// ---------------- launch ----------------

extern "C" void kernel_launch(void* const* d_in, const int* in_sizes, int n_in,
                              void* d_out, int out_size, void* d_ws, size_t ws_size,
                              hipStream_t stream) {
    const float* bfeat  = (const float*)d_in[0];
    const float* coords = (const float*)d_in[1];
    const int* mask = (const int*)d_in[2];  // jnp bool -> int32 on device
    const float* Wih0 = (const float*)d_in[3];
    const float* Whh0 = (const float*)d_in[4];
    const float* bih0 = (const float*)d_in[5];
    const float* bhh0 = (const float*)d_in[6];
    const float* Wih1 = (const float*)d_in[7];
    const float* Whh1 = (const float*)d_in[8];
    const float* bih1 = (const float*)d_in[9];
    const float* bhh1 = (const float*)d_in[10];
    const float* WihC = (const float*)d_in[11];
    // d_in[12] = WhhC: unused (coord GRU starts from h=0)
    const float* bihC = (const float*)d_in[13];
    const float* bhhC = (const float*)d_in[14];
    const float* We = (const float*)d_in[15];
    const float* be = (const float*)d_in[16];
    const float* Wc = (const float*)d_in[17];
    const float* bc_ = (const float*)d_in[18];
    const float* W1 = (const float*)d_in[19];
    const float* b1 = (const float*)d_in[20];
    const float* W2 = (const float*)d_in[21];
    const float* b2 = (const float*)d_in[22];
    float* out = (float*)d_out;

    const size_t N = NROWS;
    char* ws = (char*)d_ws;
    unsigned short* A4 = (unsigned short*)ws;                       // [N,512]
    unsigned short* A1 = (unsigned short*)ws;                       // [N,64]  (aliases A4; dead before K2)
    unsigned short* A3 = (unsigned short*)(ws + N * 512 * 2);       // [N,320]
    unsigned short* A5 = A3;                                        // [N,320] (aliases A3; A3 dead after K3)
    char* wp = ws + N * 512 * 2 + N * 320 * 2;
    unsigned short* WB0  = (unsigned short*)wp; wp += 768 * 64 * 2;
    unsigned short* WBh0 = (unsigned short*)wp; wp += 768 * 256 * 2;
    unsigned short* WB1  = (unsigned short*)wp; wp += 768 * 256 * 2;
    unsigned short* WBh1 = (unsigned short*)wp; wp += 768 * 256 * 2;
    unsigned short* WF   = (unsigned short*)wp; wp += 128 * 320 * 2;
    float* BC0 = (float*)wp; wp += 1024 * 4;
    float* BC1 = (float*)wp; wp += 1024 * 4;
    float* BF  = (float*)wp; wp += 128 * 4;

    // prep
    cvt_bf16<<<192, 256, 0, stream>>>(Wih0, WB0, 768 * 64);
    cvt3_bf16<<<768, 256, 0, stream>>>(Whh0, Wih1, Whh1, WBh0, WB1, WBh1);
    bias_prep<<<1, 256, 0, stream>>>(bih0, bhh0, BC0, bih1, bhh1, BC1);
    fuse_prep<<<160, 256, 0, stream>>>(We, be, Wc, bc_, W1, b1, WF, BF);
    xprep<<<15360, 256, 0, stream>>>(bfeat, A1, A3);

    const int gg = (NROWS / 128) * 4;  // 7680, % 8 == 0
    // K1: h0_t0 (x0, no hh, no hprev)
    gru_gemm<false, false><<<gg, 256, 0, stream>>>(A1, 64, 64, WB0, 0, nullptr, BC0, nullptr, 0, A3 + 64, 320);
    // K2: h1_t0 (h0_t0, no hh, no hprev)
    gru_gemm<false, false><<<gg, 256, 0, stream>>>(A3 + 64, 320, 256, WB1, 0, nullptr, BC1, nullptr, 0, A4 + 256, 512);
    // K3: h0_t1 (x1 + h0_t0)
    gru_gemm<true, true><<<gg, 256, 0, stream>>>(A3, 320, 64, WB0, 256, WBh0, BC0, A3 + 64, 320, A4, 512);
    // coord GRU -> A5 cols 256..319 (must run after K3: A5 aliases A3)
    coord_gru<<<NROWS / 256, 256, 0, stream>>>(coords, WihC, bihC, bhhC, A5);
    // K4: h1_t1 (h0_t1 + h1_t0) -> A5 cols 0..255
    gru_gemm<true, true><<<gg, 256, 0, stream>>>(A4, 512, 256, WB1, 256, WBh1, BC1, A4 + 256, 512, A5, 320);
    // K5: fusion + logits
    fusion_logits<<<NROWS / 64, 256, 0, stream>>>(A5, WF, BF, W2, b2, mask, out);

    (void)in_sizes; (void)n_in; (void)out_size; (void)ws_size;
}